// Round 4
// baseline (361.788 us; speedup 1.0000x reference)
//
#include <hip/hip_runtime.h>
#include <math.h>

#define Bn 128
#define Cn 64
#define Tn 500
#define CH0 252            // chunk0 covers t in [0,252), chunk1 [252,500)

__device__ __forceinline__ float elu_f(float v) {
  return v > 0.f ? v : (__expf(v) - 1.f);
}

// ---------------------------------------------------------------------------
// Stage 1: EEG feature extractor. Grid 16384 = (signal, t-chunk).
// Per block: stage x slice -> conv1(K=25)+BN+ELU -> dw(K=3)+BN+ELU -> sdw(K=3)
// -> swizzled transpose -> pointwise 16x16 +BN+ELU -> partial t-sum.
// LDS ~18.3KB -> 8 blocks/CU; __launch_bounds__(256,8) caps VGPR at 64.
__global__ __launch_bounds__(256, 8) void feat_kernel(
    const float* __restrict__ x, const float* __restrict__ w_conv1,
    const float* __restrict__ bn1, const float* __restrict__ w_dw,
    const float* __restrict__ bn2, const float* __restrict__ w_sdw,
    const float* __restrict__ w_spw, const float* __restrict__ bn3,
    float* __restrict__ fpart, float* __restrict__ gzero)
{
  __shared__ float s1[16 * 264];      // rows pitch 264: [4 zero | 256 data | 4 zero]
  __shared__ float xs[288];           // x slice: phys p <-> t = t0-16+p
  __shared__ float red[64];
  const int bid = blockIdx.x;
  const int sig = bid >> 1;
  const int chunk = bid & 1;
  const int t0 = chunk ? CH0 : 0;
  const int clen = chunk ? (Tn - CH0) : CH0;
  const int tid = threadIdx.x;
  const int o = tid & 15;             // channel
  const int tq = tid >> 4;            // 0..15

  if (bid == 0 && tid < 64) gzero[tid] = 0.f;   // zero gsum1|gsum2

  // ---- stage x (aligned float4: t0-16 is divisible by 4 for both chunks) ----
  if (tid < 72) {
    int p = tid * 4;
    int t = t0 - 16 + p;
    float4 v;
    if (t >= 0 && t + 3 < Tn) {
      v = *(const float4*)(x + sig * Tn + t);
    } else {
      float* vp = &v.x;
#pragma unroll
      for (int r = 0; r < 4; ++r) {
        int tt = t + r;
        vp[r] = (tt >= 0 && tt < Tn) ? x[sig * Tn + tt] : 0.f;
      }
    }
    *(float4*)&xs[p] = v;
  }
  if (tid < 128) {                    // zero row halos
    int row = tid >> 3, k = tid & 7;
    s1[row * 264 + (k < 4 ? k : 256 + k)] = 0.f;
  }

  float w1[25];
#pragma unroll
  for (int k = 0; k < 25; ++k) w1[k] = w_conv1[o * 25 + k];
  float sc1 = bn1[o] * rsqrtf(bn1[48 + o] + 1e-5f);
  float sh1 = bn1[16 + o] - bn1[32 + o] * sc1;

  __syncthreads();

  // ---- conv1: local L = tq*4 + p*64 + r, t = t0-2+L; x[t+k-12] = xs[L+k+2] ----
#pragma unroll
  for (int p = 0; p < 4; ++p) {
    const int L0 = tq * 4 + p * 64;
    float r0 = 0.f, r1 = 0.f, r2 = 0.f, r3 = 0.f;
#pragma unroll
    for (int c = 0; c < 8; ++c) {
      float4 xv = *(const float4*)&xs[L0 + 4 * c];
      const float* x4 = &xv.x;
#pragma unroll
      for (int jj = 0; jj < 4; ++jj) {
        const int j = 4 * c + jj;          // res[r] += xs[L0+j] * w1[j-2-r]
        float xvj = x4[jj];
        if (j - 2 >= 0 && j - 2 < 25) r0 += xvj * w1[j - 2];
        if (j - 3 >= 0 && j - 3 < 25) r1 += xvj * w1[j - 3];
        if (j - 4 >= 0 && j - 4 < 25) r2 += xvj * w1[j - 4];
        if (j - 5 >= 0 && j - 5 < 25) r3 += xvj * w1[j - 5];
      }
    }
    float4 res;
    float* rp = &res.x;
    float rr[4] = {r0, r1, r2, r3};
#pragma unroll
    for (int r = 0; r < 4; ++r) {
      int t = t0 - 2 + L0 + r;
      float v = elu_f(rr[r] * sc1 + sh1);
      rp[r] = (t >= 0 && t < Tn) ? v : 0.f;   // zero-pad outside the signal
    }
    *(float4*)&s1[o * 264 + 4 + L0] = res;
  }

  // ---- depthwise K=3 + BN + ELU (in place) ----
  float wd0 = w_dw[o * 3], wd1 = w_dw[o * 3 + 1], wd2 = w_dw[o * 3 + 2];
  float sc2 = bn2[o] * rsqrtf(bn2[48 + o] + 1e-5f);
  float sh2 = bn2[16 + o] - bn2[32 + o] * sc2;
  float dres[16];
  __syncthreads();
#pragma unroll
  for (int p = 0; p < 4; ++p) {
    const int L0 = tq * 4 + p * 64;
    const float* row = &s1[o * 264 + 4 + L0];
    float4 A = *(const float4*)(row - 4);
    float4 B = *(const float4*)(row);
    float4 C = *(const float4*)(row + 4);
    float win[6] = {A.w, B.x, B.y, B.z, B.w, C.x};
#pragma unroll
    for (int r = 0; r < 4; ++r) {
      float a = win[r] * wd0 + win[r + 1] * wd1 + win[r + 2] * wd2;
      float v = elu_f(a * sc2 + sh2);
      int t = t0 - 2 + L0 + r;
      dres[p * 4 + r] = (t >= 0 && t < Tn) ? v : 0.f;
    }
  }
  __syncthreads();
#pragma unroll
  for (int p = 0; p < 4; ++p)
    *(float4*)&s1[o * 264 + 4 + tq * 4 + p * 64] = *(float4*)&dres[p * 4];

  // ---- separable depthwise K=3 (no act) -> regs, then swizzled transpose ----
  float we0 = w_sdw[o * 3], we1 = w_sdw[o * 3 + 1], we2 = w_sdw[o * 3 + 2];
  float sres[16];
  __syncthreads();
#pragma unroll
  for (int p = 0; p < 4; ++p) {
    const int L0 = tq * 4 + p * 64;
    const float* row = &s1[o * 264 + 4 + L0];
    float4 A = *(const float4*)(row - 4);
    float4 B = *(const float4*)(row);
    float4 C = *(const float4*)(row + 4);
    float win[6] = {A.w, B.x, B.y, B.z, B.w, C.x};
#pragma unroll
    for (int r = 0; r < 4; ++r)
      sres[p * 4 + r] = win[r] * we0 + win[r + 1] * we1 + win[r + 2] * we2;
  }
  __syncthreads();
  // sT[t][16] aliases s1; chunk c of channels stored at position c ^ ((t>>1)&3)
#pragma unroll
  for (int p = 0; p < 4; ++p) {
#pragma unroll
    for (int r = 0; r < 4; ++r) {
      int lt = tq * 4 + p * 64 + r - 2;        // t - t0
      if (lt >= 0 && lt < clen) {
        int pos = (o >> 2) ^ ((lt >> 1) & 3);
        s1[lt * 16 + pos * 4 + (o & 3)] = sres[p * 4 + r];
      }
    }
  }

  // ---- pointwise 16->16 + BN + ELU + partial t-sum (one out-channel/thread) ----
  float wpr[16];
#pragma unroll
  for (int c = 0; c < 4; ++c)
    *(float4*)&wpr[4 * c] = *(const float4*)&w_spw[o * 16 + 4 * c];
  float sc3 = bn3[o] * rsqrtf(bn3[48 + o] + 1e-5f);
  float sh3 = bn3[16 + o] - bn3[32 + o] * sc3;
  float accs = 0.f;
  __syncthreads();
#pragma unroll
  for (int tt = 0; tt < 16; ++tt) {
    int lt = tq + 16 * tt;
    if (lt < clen) {
      int s = (lt >> 1) & 3;
      float a = 0.f;
#pragma unroll
      for (int c = 0; c < 4; ++c) {
        float4 vv = *(const float4*)&s1[lt * 16 + ((c ^ s) * 4)];
        a += vv.x * wpr[4 * c] + vv.y * wpr[4 * c + 1] +
             vv.z * wpr[4 * c + 2] + vv.w * wpr[4 * c + 3];
      }
      accs += elu_f(a * sc3 + sh3);
    }
  }
  accs += __shfl_xor(accs, 16, 64);
  accs += __shfl_xor(accs, 32, 64);
  if ((tid & 63) < 16) red[(tid >> 6) * 16 + o] = accs;
  __syncthreads();
  if (tid < 16)
    fpart[(chunk * (Bn * Cn) + sig) * 16 + tid] =
        red[tid] + red[16 + tid] + red[32 + tid] + red[48 + tid];
}

// ---------------------------------------------------------------------------
// GAT layer fused with: graph build (redundant per block), SE-gate apply
// (layer 2), BN + skip + GELU epilogue, SE partial sums. One block per b.
#define SM_XLS  0        // 8448  (graph phase: ne [0,1024), Ms [1024,5120))
#define SM_AL   8448     // 4352  (graph phase: Arow)
#define SM_XS   12800    // 2048
#define SM_MLG  14848    // 4096
#define SM_SS   18944    // 256
#define SM_DS   19200    // 256
#define SM_PM   19456    // 256
#define SM_PS   19712    // 256
#define SM_RM   19968    // 64
#define SM_INV  20032    // 64
#define SM_SEA  20096    // 32
#define SM_GATE 20128    // 32
#define SM_R8   20160    // 8
#define SM_TOT  20168

template <int FIN, int LAYER>
__global__ __launch_bounds__(256) void gat_kernel(
    const float* __restrict__ Xa, const float* __restrict__ Xb,
    const float* __restrict__ node_embed, const int* __restrict__ edges,
    const float* __restrict__ se_w1, const float* __restrict__ se_w2,
    const float* __restrict__ gsum_in,
    const float* __restrict__ W, const float* __restrict__ a_src,
    const float* __restrict__ a_dst, const float* __restrict__ bias,
    const float* __restrict__ bnp, const float* __restrict__ skip_w,
    float* __restrict__ out, float* __restrict__ gsum_out)
{
  __shared__ float sm[SM_TOT];
  float* xls = sm + SM_XLS;
  float* al  = sm + SM_AL;
  float* Xs  = sm + SM_XS;
  float* Mlg = sm + SM_MLG;
  float* ne  = sm + SM_XLS;          // graph-phase aliases
  float* Ms  = sm + SM_XLS + 1024;
  const int b = blockIdx.x;
  const int tid = threadIdx.x;

  // ---- phase 0: loads ----
  if (tid < 32) sm[SM_SEA + tid] = 0.f;
  if (LAYER == 2 && tid >= 32 && tid < 64)
    sm[SM_GATE + tid - 32] = gsum_in[tid - 32] * (1.f / 8192.f);
  for (int i = tid; i < 1024; i += 256) ne[i] = node_embed[i];
  for (int i = tid; i < 4096; i += 256) Ms[i] = 0.f;
  if (LAYER == 1) {
    for (int i = tid; i < 64 * FIN; i += 256)
      Xs[i] = (Xa[b * 64 * FIN + i] + Xb[b * 64 * FIN + i]) * (1.f / 500.f);
  } else {
    for (int i = tid; i < 64 * FIN; i += 256) Xs[i] = Xa[b * 64 * FIN + i];
  }
  int e0 = edges[tid], e1 = edges[256 + tid];
  __syncthreads();

  // ---- phase 1: A = relu(ne ne^T) (al), edge scatter (Ms), SE hidden ----
  for (int idx = tid; idx < 4096; idx += 256) {
    int i = idx >> 6, j = idx & 63;
    float a = 0.f;
#pragma unroll
    for (int f = 0; f < 16; ++f) a += ne[i * 16 + f] * ne[j * 16 + f];
    al[i * 68 + j] = a > 0.f ? a : 0.f;
  }
  atomicAdd(&Ms[e0 * 64 + e1], 1.f);
  if (LAYER == 2 && tid < 8) {
    float a = 0.f;
    for (int f = 0; f < 32; ++f) a += sm[SM_GATE + f] * se_w1[tid * 32 + f];
    sm[SM_R8 + tid] = a > 0.f ? a : 0.f;
  }
  __syncthreads();

  // ---- phase 2: row sums; SE gate ----
  if (tid < 64) {
    float s = 0.f;
    for (int j = 0; j < 64; ++j) s += al[tid * 68 + j];
    sm[SM_RM + tid] = s + 1e-6f;
  }
  if (LAYER == 2 && tid >= 64 && tid < 96) {
    float a = 0.f;
    for (int k = 0; k < 8; ++k) a += sm[SM_R8 + k] * se_w2[(tid - 64) * 8 + k];
    sm[SM_GATE + tid - 64] = 1.f / (1.f + __expf(-a));
  }
  __syncthreads();

  // ---- phase 3: Mlg; apply gate to Xs (layer 2) ----
  for (int idx = tid; idx < 4096; idx += 256) {
    int i = idx >> 6, j = idx & 63;
    float dyn = (al[i * 68 + j] / sm[SM_RM + i] > 0.1f) ? 1.f : 0.f;
    float M = (i == j) ? 1.f : (Ms[idx] + dyn);
    Mlg[idx] = (M > 0.f) ? logf(M) : -INFINITY;
  }
  if (LAYER == 2) {
    for (int i = tid; i < 64 * FIN; i += 256) Xs[i] *= sm[SM_GATE + (i & 31)];
  }
  __syncthreads();

  // ---- projection xl = X W into xls (pitch 132) ----
  {
    const int fo = tid & 127, half = tid >> 7;
    float wcol[FIN];
#pragma unroll
    for (int q = 0; q < FIN; ++q) wcol[q] = W[q * 128 + fo];
    for (int nn = half; nn < 64; nn += 2) {
      float acc = 0.f;
#pragma unroll
      for (int q = 0; q < FIN; ++q) acc += Xs[nn * FIN + q] * wcol[q];
      xls[nn * 132 + fo] = acc;
    }
  }
  __syncthreads();

  // ---- attention src/dst terms ----
  {
    const int nn = tid >> 2, h = tid & 3;
    float s = 0.f, d = 0.f;
    for (int q = 0; q < 32; ++q) {
      float xv = xls[nn * 132 + h * 32 + q];
      s += xv * a_src[h * 32 + q];
      d += xv * a_dst[h * 32 + q];
    }
    sm[SM_SS + nn * 4 + h] = s;
    sm[SM_DS + nn * 4 + h] = d;
  }

  float accH[2][4];
#pragma unroll
  for (int ii = 0; ii < 2; ++ii)
#pragma unroll
    for (int r = 0; r < 4; ++r) accH[ii][r] = 0.f;

  const int q4 = tid & 7;
  const int ig = tid >> 3;

  for (int h = 0; h < 4; ++h) {
    __syncthreads();
    for (int idx = tid; idx < 4096; idx += 256) {
      int i = idx >> 6, j = idx & 63;
      float e = sm[SM_DS + i * 4 + h] + sm[SM_SS + j * 4 + h];
      e = e >= 0.f ? e : 0.2f * e;
      al[i * 68 + j] = e + Mlg[idx];
    }
    __syncthreads();
    {
      const int i = tid >> 2, c = tid & 3;
      float mx = -INFINITY;
      for (int jj = 0; jj < 16; ++jj) mx = fmaxf(mx, al[i * 68 + c * 16 + jj]);
      sm[SM_PM + tid] = mx;
    }
    __syncthreads();
    if (tid < 64)
      sm[SM_RM + tid] = fmaxf(fmaxf(sm[SM_PM + tid * 4], sm[SM_PM + tid * 4 + 1]),
                              fmaxf(sm[SM_PM + tid * 4 + 2], sm[SM_PM + tid * 4 + 3]));
    __syncthreads();
    {
      const int i = tid >> 2, c = tid & 3;
      float r = sm[SM_RM + i], s = 0.f;
      for (int jj = 0; jj < 16; ++jj) {
        float v = __expf(al[i * 68 + c * 16 + jj] - r);
        al[i * 68 + c * 16 + jj] = v;
        s += v;
      }
      sm[SM_PS + tid] = s;
    }
    __syncthreads();
    if (tid < 64)
      sm[SM_INV + tid] = 1.f / (sm[SM_PS + tid * 4] + sm[SM_PS + tid * 4 + 1] +
                                sm[SM_PS + tid * 4 + 2] + sm[SM_PS + tid * 4 + 3]);
    __syncthreads();
#pragma unroll
    for (int ii = 0; ii < 2; ++ii) {
      const int i = ig * 2 + ii;
      float a0 = 0.f, a1 = 0.f, a2 = 0.f, a3 = 0.f;
      for (int j = 0; j < 64; ++j) {
        float av = al[i * 68 + j];
        const float4 xv = *(const float4*)&xls[j * 132 + h * 32 + q4 * 4];
        a0 += av * xv.x; a1 += av * xv.y; a2 += av * xv.z; a3 += av * xv.w;
      }
      const float iv = sm[SM_INV + i];
      accH[ii][0] += a0 * iv; accH[ii][1] += a1 * iv;
      accH[ii][2] += a2 * iv; accH[ii][3] += a3 * iv;
    }
  }

  // ---- epilogue ----
  float bscale[4], bshift[4], bi[4];
#pragma unroll
  for (int r = 0; r < 4; ++r) {
    int f = q4 * 4 + r;
    float g = bnp[f], be = bnp[32 + f], m = bnp[64 + f], v = bnp[96 + f];
    bscale[r] = g * rsqrtf(v + 1e-5f);
    bshift[r] = be - m * bscale[r];
    bi[r] = bias[f];
  }
#pragma unroll
  for (int ii = 0; ii < 2; ++ii) {
    const int i = ig * 2 + ii;
    float res[4];
#pragma unroll
    for (int r = 0; r < 4; ++r) {
      int f = q4 * 4 + r;
      float v = accH[ii][r] * 0.25f + bi[r];
      v = v * bscale[r] + bshift[r];
      float skip;
      if (LAYER == 1) {
        skip = 0.f;
#pragma unroll
        for (int q = 0; q < 16; ++q) skip += Xs[i * 16 + q] * skip_w[f * 16 + q];
      } else {
        skip = Xs[i * 32 + f];
      }
      v += skip;
      v = 0.5f * v * (1.f + erff(v * 0.70710678118654752440f));
      res[r] = v;
      atomicAdd(&sm[SM_SEA + f], v);
    }
    float4* op = (float4*)&out[(b * 64 + i) * 32 + q4 * 4];
    *op = make_float4(res[0], res[1], res[2], res[3]);
  }
  __syncthreads();
  if (tid < 32) atomicAdd(&gsum_out[tid], sm[SM_SEA + tid]);
}

// ---------------------------------------------------------------------------
// SE2 gate (redundant per block) + pool over C + classifier.
__global__ __launch_bounds__(64) void out_kernel(
    const float* __restrict__ tmp2, const float* __restrict__ gsum2,
    const float* __restrict__ se_w1, const float* __restrict__ se_w2,
    const float* __restrict__ clf_w, const float* __restrict__ clf_b,
    float* __restrict__ outp)
{
  __shared__ float mean32[32], r8[8], gate[32], pl[32];
  const int b = blockIdx.x, tid = threadIdx.x;
  if (tid < 32) mean32[tid] = gsum2[tid] * (1.f / 8192.f);
  __syncthreads();
  if (tid < 8) {
    float a = 0.f;
    for (int f = 0; f < 32; ++f) a += mean32[f] * se_w1[tid * 32 + f];
    r8[tid] = a > 0.f ? a : 0.f;
  }
  __syncthreads();
  if (tid < 32) {
    float a = 0.f;
    for (int k = 0; k < 8; ++k) a += r8[k] * se_w2[tid * 8 + k];
    gate[tid] = 1.f / (1.f + __expf(-a));
  }
  __syncthreads();
  if (tid < 32) {
    float a = 0.f;
    for (int n = 0; n < 64; ++n) a += tmp2[(b * 64 + n) * 32 + tid];
    pl[tid] = a * (1.f / 64.f) * gate[tid];
  }
  __syncthreads();
  if (tid < 2) {
    float a = clf_b[tid];
    for (int f = 0; f < 32; ++f) a += pl[f] * clf_w[tid * 32 + f];
    outp[b * 2 + tid] = a;
  }
}

// ---------------------------------------------------------------------------
extern "C" void kernel_launch(void* const* d_in, const int* in_sizes, int n_in,
                              void* d_out, int out_size, void* d_ws, size_t ws_size,
                              hipStream_t stream)
{
  const float* x          = (const float*)d_in[0];
  const int*   edges      = (const int*)d_in[1];
  const float* conv1_w    = (const float*)d_in[2];
  const float* bn_c1      = (const float*)d_in[3];
  const float* dw_w       = (const float*)d_in[4];
  const float* bn_c2      = (const float*)d_in[5];
  const float* sdw_w      = (const float*)d_in[6];
  const float* spw_w      = (const float*)d_in[7];
  const float* bn_c3      = (const float*)d_in[8];
  const float* node_embed = (const float*)d_in[9];
  const float* gat1_w     = (const float*)d_in[10];
  const float* gat1_asrc  = (const float*)d_in[11];
  const float* gat1_adst  = (const float*)d_in[12];
  const float* gat1_bias  = (const float*)d_in[13];
  const float* bn_g1      = (const float*)d_in[14];
  const float* skip1_w    = (const float*)d_in[15];
  const float* se1_w1     = (const float*)d_in[16];
  const float* se1_w2     = (const float*)d_in[17];
  const float* gat2_w     = (const float*)d_in[18];
  const float* gat2_asrc  = (const float*)d_in[19];
  const float* gat2_adst  = (const float*)d_in[20];
  const float* gat2_bias  = (const float*)d_in[21];
  const float* bn_g2      = (const float*)d_in[22];
  const float* se2_w1     = (const float*)d_in[23];
  const float* se2_w2     = (const float*)d_in[24];
  const float* clf_w      = (const float*)d_in[25];
  const float* clf_b      = (const float*)d_in[26];

  float* ws   = (float*)d_ws;
  float* tmp1 = ws;             // 262144 floats  [B*C, 32]
  float* zB   = ws + 262144;    // 262144: fpart (2 x 8192 x 16), later tmp2
  float* gs   = ws + 524288;    // 64: gsum1[32] | gsum2[32]

  feat_kernel<<<Bn * Cn * 2, 256, 0, stream>>>(x, conv1_w, bn_c1, dw_w, bn_c2,
                                               sdw_w, spw_w, bn_c3, zB, gs);
  gat_kernel<16, 1><<<Bn, 256, 0, stream>>>(
      zB, zB + 131072, node_embed, edges, nullptr, nullptr, nullptr,
      gat1_w, gat1_asrc, gat1_adst, gat1_bias, bn_g1, skip1_w, tmp1, gs);
  gat_kernel<32, 2><<<Bn, 256, 0, stream>>>(
      tmp1, nullptr, node_embed, edges, se1_w1, se1_w2, gs,
      gat2_w, gat2_asrc, gat2_adst, gat2_bias, bn_g2, nullptr, zB, gs + 32);
  out_kernel<<<Bn, 64, 0, stream>>>(zB, gs + 32, se2_w1, se2_w2, clf_w, clf_b,
                                    (float*)d_out);
}

// Round 5
// 297.563 us; speedup vs baseline: 1.2158x; 1.2158x over previous
//
#include <hip/hip_runtime.h>
#include <math.h>

#define Bn 128
#define Cn 64
#define Tn 500

typedef float v2f __attribute__((ext_vector_type(2)));

__device__ __forceinline__ v2f elu2(v2f v) {
  // elu(v) = exp(min(v,0)) - 1 + max(v,0)   (branch/select-free, packable)
  v2f z; z.x = 0.f; z.y = 0.f;
  v2f mn = __builtin_elementwise_min(v, z);
  v2f mx = __builtin_elementwise_max(v, z);
  v2f e; e.x = __expf(mn.x); e.y = __expf(mn.y);
  return e - 1.f + mx;
}

// ---------------------------------------------------------------------------
// Stage 1: EEG feature extractor. One block per signal (8192 blocks).
// Thread = (op = tid&7: channel PAIR 2op,2op+1 packed in v2f) x (tg = tid>>3:
// 16 contiguous t). conv1 computed over extended t range [T0-2, T0+18) in
// registers -> dw -> sdw all register-local (no halo exchange). One LDS store
// of the sdw result (channel-pair rows, pitch 522) feeds the pointwise stage.
// All FMAs are v2f -> v_pk_fma_f32 (2 channels / instruction).
__global__ __launch_bounds__(256, 4) void feat_kernel(
    const float* __restrict__ x, const float* __restrict__ w_conv1,
    const float* __restrict__ bn1, const float* __restrict__ w_dw,
    const float* __restrict__ bn2, const float* __restrict__ w_sdw,
    const float* __restrict__ w_spw, const float* __restrict__ bn3,
    float* __restrict__ feats, float* __restrict__ gzero)
{
  __shared__ float xs[544];          // xs[p] = x[p-16], zero-padded both sides
  __shared__ v2f   wL[200];          // conv1 weight pairs [op][k]
  __shared__ v2f   s1p[8 * 522];     // sdw result, rows per channel-pair
  __shared__ float red[64];
  const int n = blockIdx.x;
  const int tid = threadIdx.x;
  const int op = tid & 7;            // channel pair (2op, 2op+1)
  const int tg = tid >> 3;           // 0..31, t in [16tg, 16tg+16)
  const int T0 = tg * 16;

  if (n == 0 && tid < 64) gzero[tid] = 0.f;   // zero gsum1|gsum2

  // ---- stage x and conv1 weight pairs ----
  if (tid < 125) *(float4*)&xs[16 + 4 * tid] = ((const float4*)(x + n * Tn))[tid];
  if (tid < 16) xs[tid] = 0.f;
  else if (tid < 44) xs[500 + tid] = 0.f;     // p in [516, 544)
  if (tid < 200) {
    int kk = tid % 25, opp = tid / 25;
    v2f w; w.x = w_conv1[opp * 50 + kk]; w.y = w_conv1[opp * 50 + 25 + kk];
    wL[opp * 25 + kk] = w;
  }

  // per-pair BN constants
  v2f sc1, sh1, sc2, sh2, sc3, sh3;
  {
    int c0 = 2 * op, c1 = 2 * op + 1;
    sc1.x = bn1[c0] * rsqrtf(bn1[48 + c0] + 1e-5f);
    sc1.y = bn1[c1] * rsqrtf(bn1[48 + c1] + 1e-5f);
    sh1.x = bn1[16 + c0] - bn1[32 + c0] * sc1.x;
    sh1.y = bn1[16 + c1] - bn1[32 + c1] * sc1.y;
    sc2.x = bn2[c0] * rsqrtf(bn2[48 + c0] + 1e-5f);
    sc2.y = bn2[c1] * rsqrtf(bn2[48 + c1] + 1e-5f);
    sh2.x = bn2[16 + c0] - bn2[32 + c0] * sc2.x;
    sh2.y = bn2[16 + c1] - bn2[32 + c1] * sc2.y;
  }
  v2f wd[3], we[3];
#pragma unroll
  for (int k = 0; k < 3; ++k) {
    wd[k].x = w_dw[6 * op + k];     wd[k].y = w_dw[6 * op + 3 + k];
    we[k].x = w_sdw[6 * op + k];    we[k].y = w_sdw[6 * op + 3 + k];
  }
  __syncthreads();

  // ---- conv1 (K=25) over extended range t in [T0-2, T0+18), + BN + ELU ----
  // window xw[i] = xs[T0 + i], i in [0,48); y(t) uses xs[t+k+4] (k 0..24)
  float xw[48];
#pragma unroll
  for (int i = 0; i < 12; ++i) *(float4*)&xw[4 * i] = *(const float4*)&xs[T0 + 4 * i];
  v2f ce[20];
#pragma unroll
  for (int j = 0; j < 20; ++j) { ce[j].x = 0.f; ce[j].y = 0.f; }
#pragma unroll
  for (int k = 0; k < 25; ++k) {
    v2f wt = wL[op * 25 + k];
#pragma unroll
    for (int j = 0; j < 20; ++j) ce[j] += wt * xw[j + k + 2];
  }
  v2f zero; zero.x = 0.f; zero.y = 0.f;
#pragma unroll
  for (int j = 0; j < 20; ++j) {
    int t = T0 - 2 + j;
    v2f v = elu2(ce[j] * sc1 + sh1);
    ce[j] = ((unsigned)t < (unsigned)Tn) ? v : zero;  // dw's zero padding
  }

  // ---- depthwise K=3 + BN + ELU, t in [T0-1, T0+17) ----
  v2f d[18];
#pragma unroll
  for (int j = 0; j < 18; ++j) {
    int t = T0 - 1 + j;
    v2f a = ce[j] * wd[0] + ce[j + 1] * wd[1] + ce[j + 2] * wd[2];
    v2f v = elu2(a * sc2 + sh2);
    d[j] = ((unsigned)t < (unsigned)Tn) ? v : zero;
  }

  // ---- separable depthwise K=3 (no act), t in [T0, T0+16) -> LDS ----
#pragma unroll
  for (int r = 0; r < 8; ++r) {
    v2f s0 = d[2 * r] * we[0] + d[2 * r + 1] * we[1] + d[2 * r + 2] * we[2];
    v2f s1 = d[2 * r + 1] * we[0] + d[2 * r + 2] * we[1] + d[2 * r + 3] * we[2];
    float4 st; st.x = s0.x; st.y = s0.y; st.z = s1.x; st.w = s1.y;
    *(float4*)&s1p[op * 522 + T0 + 2 * r] = st;
  }

  // ---- pointwise 16->16 + BN + ELU + t-sum. Thread = (oq = tid&3: 4 out
  // channels as two v2f pairs) x (tgp = tid>>2: t = tgp + 64*tt) ----
  const int oq = tid & 3, tgp = tid >> 2;
  v2f wA[16], wB[16];
#pragma unroll
  for (int q = 0; q < 16; ++q) {
    wA[q].x = w_spw[(4 * oq) * 16 + q];     wA[q].y = w_spw[(4 * oq + 1) * 16 + q];
    wB[q].x = w_spw[(4 * oq + 2) * 16 + q]; wB[q].y = w_spw[(4 * oq + 3) * 16 + q];
  }
  {
    int c0 = 4 * oq;
    sc3.x = bn3[c0] * rsqrtf(bn3[48 + c0] + 1e-5f);
    sc3.y = bn3[c0 + 1] * rsqrtf(bn3[48 + c0 + 1] + 1e-5f);
    sh3.x = bn3[16 + c0] - bn3[32 + c0] * sc3.x;
    sh3.y = bn3[16 + c0 + 1] - bn3[32 + c0 + 1] * sc3.y;
  }
  v2f sc3b, sh3b;
  {
    int c0 = 4 * oq + 2;
    sc3b.x = bn3[c0] * rsqrtf(bn3[48 + c0] + 1e-5f);
    sc3b.y = bn3[c0 + 1] * rsqrtf(bn3[48 + c0 + 1] + 1e-5f);
    sh3b.x = bn3[16 + c0] - bn3[32 + c0] * sc3b.x;
    sh3b.y = bn3[16 + c0 + 1] - bn3[32 + c0 + 1] * sc3b.y;
  }
  v2f tsA = zero, tsB = zero;
  __syncthreads();
#pragma unroll
  for (int tt = 0; tt < 8; ++tt) {
    int t = tgp + 64 * tt;
    if (tt < 7 || tgp < Tn - 448) {
      v2f aA = zero, aB = zero;
#pragma unroll
      for (int opr = 0; opr < 8; ++opr) {
        v2f inq = s1p[opr * 522 + t];
        aA += wA[2 * opr] * inq.x;  aA += wA[2 * opr + 1] * inq.y;
        aB += wB[2 * opr] * inq.x;  aB += wB[2 * opr + 1] * inq.y;
      }
      tsA += elu2(aA * sc3 + sh3);
      tsB += elu2(aB * sc3b + sh3b);
    }
  }
  // reduce over tgp within wave (lane bits 2..5), then across waves via LDS
#pragma unroll
  for (int dd = 4; dd <= 32; dd <<= 1) {
    tsA.x += __shfl_xor(tsA.x, dd, 64); tsA.y += __shfl_xor(tsA.y, dd, 64);
    tsB.x += __shfl_xor(tsB.x, dd, 64); tsB.y += __shfl_xor(tsB.y, dd, 64);
  }
  if ((tid & 63) < 4) {
    float4 st; st.x = tsA.x; st.y = tsA.y; st.z = tsB.x; st.w = tsB.y;
    *(float4*)&red[(tid >> 6) * 16 + oq * 4] = st;
  }
  __syncthreads();
  if (tid < 16)
    feats[n * 16 + tid] =
        (red[tid] + red[16 + tid] + red[32 + tid] + red[48 + tid]) * (1.f / 500.f);
}

// ---------------------------------------------------------------------------
// GAT layer fused with: graph build (redundant per block), SE-gate apply
// (layer 2), BN + skip + GELU epilogue, SE partial sums. One block per b.
#define SM_XLS  0        // 8448  (graph phase: ne [0,1024), Ms [1024,5120))
#define SM_AL   8448     // 4352  (graph phase: Arow)
#define SM_XS   12800    // 2048
#define SM_MLG  14848    // 4096
#define SM_SS   18944    // 256
#define SM_DS   19200    // 256
#define SM_PM   19456    // 256
#define SM_PS   19712    // 256
#define SM_RM   19968    // 64
#define SM_INV  20032    // 64
#define SM_SEA  20096    // 32
#define SM_GATE 20128    // 32
#define SM_R8   20160    // 8
#define SM_TOT  20168

template <int FIN, int LAYER>
__global__ __launch_bounds__(256) void gat_kernel(
    const float* __restrict__ Xa,
    const float* __restrict__ node_embed, const int* __restrict__ edges,
    const float* __restrict__ se_w1, const float* __restrict__ se_w2,
    const float* __restrict__ gsum_in,
    const float* __restrict__ W, const float* __restrict__ a_src,
    const float* __restrict__ a_dst, const float* __restrict__ bias,
    const float* __restrict__ bnp, const float* __restrict__ skip_w,
    float* __restrict__ out, float* __restrict__ gsum_out)
{
  __shared__ float sm[SM_TOT];
  float* xls = sm + SM_XLS;
  float* al  = sm + SM_AL;
  float* Xs  = sm + SM_XS;
  float* Mlg = sm + SM_MLG;
  float* ne  = sm + SM_XLS;          // graph-phase aliases
  float* Ms  = sm + SM_XLS + 1024;
  const int b = blockIdx.x;
  const int tid = threadIdx.x;

  // ---- phase 0: loads ----
  if (tid < 32) sm[SM_SEA + tid] = 0.f;
  if (LAYER == 2 && tid >= 32 && tid < 64)
    sm[SM_GATE + tid - 32] = gsum_in[tid - 32] * (1.f / 8192.f);
  for (int i = tid; i < 1024; i += 256) ne[i] = node_embed[i];
  for (int i = tid; i < 4096; i += 256) Ms[i] = 0.f;
  for (int i = tid; i < 64 * FIN; i += 256) Xs[i] = Xa[b * 64 * FIN + i];
  int e0 = edges[tid], e1 = edges[256 + tid];
  __syncthreads();

  // ---- phase 1: A = relu(ne ne^T) (al), edge scatter (Ms), SE hidden ----
  for (int idx = tid; idx < 4096; idx += 256) {
    int i = idx >> 6, j = idx & 63;
    float a = 0.f;
#pragma unroll
    for (int f = 0; f < 16; ++f) a += ne[i * 16 + f] * ne[j * 16 + f];
    al[i * 68 + j] = a > 0.f ? a : 0.f;
  }
  atomicAdd(&Ms[e0 * 64 + e1], 1.f);
  if (LAYER == 2 && tid < 8) {
    float a = 0.f;
    for (int f = 0; f < 32; ++f) a += sm[SM_GATE + f] * se_w1[tid * 32 + f];
    sm[SM_R8 + tid] = a > 0.f ? a : 0.f;
  }
  __syncthreads();

  // ---- phase 2: row sums; SE gate ----
  if (tid < 64) {
    float s = 0.f;
    for (int j = 0; j < 64; ++j) s += al[tid * 68 + j];
    sm[SM_RM + tid] = s + 1e-6f;
  }
  if (LAYER == 2 && tid >= 64 && tid < 96) {
    float a = 0.f;
    for (int k = 0; k < 8; ++k) a += sm[SM_R8 + k] * se_w2[(tid - 64) * 8 + k];
    sm[SM_GATE + tid - 64] = 1.f / (1.f + __expf(-a));
  }
  __syncthreads();

  // ---- phase 3: Mlg; apply gate to Xs (layer 2) ----
  for (int idx = tid; idx < 4096; idx += 256) {
    int i = idx >> 6, j = idx & 63;
    float dyn = (al[i * 68 + j] / sm[SM_RM + i] > 0.1f) ? 1.f : 0.f;
    float M = (i == j) ? 1.f : (Ms[idx] + dyn);
    Mlg[idx] = (M > 0.f) ? logf(M) : -INFINITY;
  }
  if (LAYER == 2) {
    for (int i = tid; i < 64 * FIN; i += 256) Xs[i] *= sm[SM_GATE + (i & 31)];
  }
  __syncthreads();

  // ---- projection xl = X W into xls (pitch 132) ----
  {
    const int fo = tid & 127, half = tid >> 7;
    float wcol[FIN];
#pragma unroll
    for (int q = 0; q < FIN; ++q) wcol[q] = W[q * 128 + fo];
    for (int nn = half; nn < 64; nn += 2) {
      float acc = 0.f;
#pragma unroll
      for (int q = 0; q < FIN; ++q) acc += Xs[nn * FIN + q] * wcol[q];
      xls[nn * 132 + fo] = acc;
    }
  }
  __syncthreads();

  // ---- attention src/dst terms ----
  {
    const int nn = tid >> 2, h = tid & 3;
    float s = 0.f, d = 0.f;
    for (int q = 0; q < 32; ++q) {
      float xv = xls[nn * 132 + h * 32 + q];
      s += xv * a_src[h * 32 + q];
      d += xv * a_dst[h * 32 + q];
    }
    sm[SM_SS + nn * 4 + h] = s;
    sm[SM_DS + nn * 4 + h] = d;
  }

  float accH[2][4];
#pragma unroll
  for (int ii = 0; ii < 2; ++ii)
#pragma unroll
    for (int r = 0; r < 4; ++r) accH[ii][r] = 0.f;

  const int q4 = tid & 7;
  const int ig = tid >> 3;

  for (int h = 0; h < 4; ++h) {
    __syncthreads();
    for (int idx = tid; idx < 4096; idx += 256) {
      int i = idx >> 6, j = idx & 63;
      float e = sm[SM_DS + i * 4 + h] + sm[SM_SS + j * 4 + h];
      e = e >= 0.f ? e : 0.2f * e;
      al[i * 68 + j] = e + Mlg[idx];
    }
    __syncthreads();
    {
      const int i = tid >> 2, c = tid & 3;
      float mx = -INFINITY;
      for (int jj = 0; jj < 16; ++jj) mx = fmaxf(mx, al[i * 68 + c * 16 + jj]);
      sm[SM_PM + tid] = mx;
    }
    __syncthreads();
    if (tid < 64)
      sm[SM_RM + tid] = fmaxf(fmaxf(sm[SM_PM + tid * 4], sm[SM_PM + tid * 4 + 1]),
                              fmaxf(sm[SM_PM + tid * 4 + 2], sm[SM_PM + tid * 4 + 3]));
    __syncthreads();
    {
      const int i = tid >> 2, c = tid & 3;
      float r = sm[SM_RM + i], s = 0.f;
      for (int jj = 0; jj < 16; ++jj) {
        float v = __expf(al[i * 68 + c * 16 + jj] - r);
        al[i * 68 + c * 16 + jj] = v;
        s += v;
      }
      sm[SM_PS + tid] = s;
    }
    __syncthreads();
    if (tid < 64)
      sm[SM_INV + tid] = 1.f / (sm[SM_PS + tid * 4] + sm[SM_PS + tid * 4 + 1] +
                                sm[SM_PS + tid * 4 + 2] + sm[SM_PS + tid * 4 + 3]);
    __syncthreads();
#pragma unroll
    for (int ii = 0; ii < 2; ++ii) {
      const int i = ig * 2 + ii;
      float a0 = 0.f, a1 = 0.f, a2 = 0.f, a3 = 0.f;
      for (int j = 0; j < 64; ++j) {
        float av = al[i * 68 + j];
        const float4 xv = *(const float4*)&xls[j * 132 + h * 32 + q4 * 4];
        a0 += av * xv.x; a1 += av * xv.y; a2 += av * xv.z; a3 += av * xv.w;
      }
      const float iv = sm[SM_INV + i];
      accH[ii][0] += a0 * iv; accH[ii][1] += a1 * iv;
      accH[ii][2] += a2 * iv; accH[ii][3] += a3 * iv;
    }
  }

  // ---- epilogue ----
  float bscale[4], bshift[4], bi[4];
#pragma unroll
  for (int r = 0; r < 4; ++r) {
    int f = q4 * 4 + r;
    float g = bnp[f], be = bnp[32 + f], m = bnp[64 + f], v = bnp[96 + f];
    bscale[r] = g * rsqrtf(v + 1e-5f);
    bshift[r] = be - m * bscale[r];
    bi[r] = bias[f];
  }
#pragma unroll
  for (int ii = 0; ii < 2; ++ii) {
    const int i = ig * 2 + ii;
    float res[4];
#pragma unroll
    for (int r = 0; r < 4; ++r) {
      int f = q4 * 4 + r;
      float v = accH[ii][r] * 0.25f + bi[r];
      v = v * bscale[r] + bshift[r];
      float skip;
      if (LAYER == 1) {
        skip = 0.f;
#pragma unroll
        for (int q = 0; q < 16; ++q) skip += Xs[i * 16 + q] * skip_w[f * 16 + q];
      } else {
        skip = Xs[i * 32 + f];
      }
      v += skip;
      v = 0.5f * v * (1.f + erff(v * 0.70710678118654752440f));
      res[r] = v;
      atomicAdd(&sm[SM_SEA + f], v);
    }
    float4* opt = (float4*)&out[(b * 64 + i) * 32 + q4 * 4];
    *opt = make_float4(res[0], res[1], res[2], res[3]);
  }
  __syncthreads();
  if (tid < 32) atomicAdd(&gsum_out[tid], sm[SM_SEA + tid]);
}

// ---------------------------------------------------------------------------
// SE2 gate (redundant per block) + pool over C + classifier.
__global__ __launch_bounds__(64) void out_kernel(
    const float* __restrict__ tmp2, const float* __restrict__ gsum2,
    const float* __restrict__ se_w1, const float* __restrict__ se_w2,
    const float* __restrict__ clf_w, const float* __restrict__ clf_b,
    float* __restrict__ outp)
{
  __shared__ float mean32[32], r8[8], gate[32], pl[32];
  const int b = blockIdx.x, tid = threadIdx.x;
  if (tid < 32) mean32[tid] = gsum2[tid] * (1.f / 8192.f);
  __syncthreads();
  if (tid < 8) {
    float a = 0.f;
    for (int f = 0; f < 32; ++f) a += mean32[f] * se_w1[tid * 32 + f];
    r8[tid] = a > 0.f ? a : 0.f;
  }
  __syncthreads();
  if (tid < 32) {
    float a = 0.f;
    for (int k = 0; k < 8; ++k) a += r8[k] * se_w2[tid * 8 + k];
    gate[tid] = 1.f / (1.f + __expf(-a));
  }
  __syncthreads();
  if (tid < 32) {
    float a = 0.f;
    for (int n = 0; n < 64; ++n) a += tmp2[(b * 64 + n) * 32 + tid];
    pl[tid] = a * (1.f / 64.f) * gate[tid];
  }
  __syncthreads();
  if (tid < 2) {
    float a = clf_b[tid];
    for (int f = 0; f < 32; ++f) a += pl[f] * clf_w[tid * 32 + f];
    outp[b * 2 + tid] = a;
  }
}

// ---------------------------------------------------------------------------
extern "C" void kernel_launch(void* const* d_in, const int* in_sizes, int n_in,
                              void* d_out, int out_size, void* d_ws, size_t ws_size,
                              hipStream_t stream)
{
  const float* x          = (const float*)d_in[0];
  const int*   edges      = (const int*)d_in[1];
  const float* conv1_w    = (const float*)d_in[2];
  const float* bn_c1      = (const float*)d_in[3];
  const float* dw_w       = (const float*)d_in[4];
  const float* bn_c2      = (const float*)d_in[5];
  const float* sdw_w      = (const float*)d_in[6];
  const float* spw_w      = (const float*)d_in[7];
  const float* bn_c3      = (const float*)d_in[8];
  const float* node_embed = (const float*)d_in[9];
  const float* gat1_w     = (const float*)d_in[10];
  const float* gat1_asrc  = (const float*)d_in[11];
  const float* gat1_adst  = (const float*)d_in[12];
  const float* gat1_bias  = (const float*)d_in[13];
  const float* bn_g1      = (const float*)d_in[14];
  const float* skip1_w    = (const float*)d_in[15];
  const float* se1_w1     = (const float*)d_in[16];
  const float* se1_w2     = (const float*)d_in[17];
  const float* gat2_w     = (const float*)d_in[18];
  const float* gat2_asrc  = (const float*)d_in[19];
  const float* gat2_adst  = (const float*)d_in[20];
  const float* gat2_bias  = (const float*)d_in[21];
  const float* bn_g2      = (const float*)d_in[22];
  const float* se2_w1     = (const float*)d_in[23];
  const float* se2_w2     = (const float*)d_in[24];
  const float* clf_w      = (const float*)d_in[25];
  const float* clf_b      = (const float*)d_in[26];

  float* ws    = (float*)d_ws;
  float* feats = ws;             // 131072 floats  [B*C, 16]
  float* tmp1  = ws + 131072;    // 262144         [B*C, 32]
  float* tmp2  = ws + 393216;    // 262144         [B*C, 32]
  float* gs    = ws + 655360;    // 64: gsum1[32] | gsum2[32]

  feat_kernel<<<Bn * Cn, 256, 0, stream>>>(x, conv1_w, bn_c1, dw_w, bn_c2,
                                           sdw_w, spw_w, bn_c3, feats, gs);
  gat_kernel<16, 1><<<Bn, 256, 0, stream>>>(
      feats, node_embed, edges, nullptr, nullptr, nullptr,
      gat1_w, gat1_asrc, gat1_adst, gat1_bias, bn_g1, skip1_w, tmp1, gs);
  gat_kernel<32, 2><<<Bn, 256, 0, stream>>>(
      tmp1, node_embed, edges, se1_w1, se1_w2, gs,
      gat2_w, gat2_asrc, gat2_adst, gat2_bias, bn_g2, nullptr, tmp2, gs + 32);
  out_kernel<<<Bn, 64, 0, stream>>>(tmp2, gs + 32, se2_w1, se2_w2, clf_w, clf_b,
                                    (float*)d_out);
}

// Round 6
// 271.596 us; speedup vs baseline: 1.3321x; 1.0956x over previous
//
#include <hip/hip_runtime.h>
#include <math.h>

#define Bn 128
#define Cn 64
#define Tn 500

typedef float v2f __attribute__((ext_vector_type(2)));

__device__ __forceinline__ v2f elu2(v2f v) {
  // elu(v) = exp(min(v,0)) - 1 + max(v,0)   (branch/select-free, packable)
  v2f z; z.x = 0.f; z.y = 0.f;
  v2f mn = __builtin_elementwise_min(v, z);
  v2f mx = __builtin_elementwise_max(v, z);
  v2f e; e.x = __expf(mn.x); e.y = __expf(mn.y);
  return e - 1.f + mx;
}

// ---------------------------------------------------------------------------
// Stage 1: EEG feature extractor (unchanged from R5). One block per signal.
__global__ __launch_bounds__(256, 4) void feat_kernel(
    const float* __restrict__ x, const float* __restrict__ w_conv1,
    const float* __restrict__ bn1, const float* __restrict__ w_dw,
    const float* __restrict__ bn2, const float* __restrict__ w_sdw,
    const float* __restrict__ w_spw, const float* __restrict__ bn3,
    float* __restrict__ feats, float* __restrict__ gzero)
{
  __shared__ float xs[544];
  __shared__ v2f   wL[200];
  __shared__ v2f   s1p[8 * 522];
  __shared__ float red[64];
  const int n = blockIdx.x;
  const int tid = threadIdx.x;
  const int op = tid & 7;
  const int tg = tid >> 3;
  const int T0 = tg * 16;

  if (n == 0 && tid < 64) gzero[tid] = 0.f;

  if (tid < 125) *(float4*)&xs[16 + 4 * tid] = ((const float4*)(x + n * Tn))[tid];
  if (tid < 16) xs[tid] = 0.f;
  else if (tid < 44) xs[500 + tid] = 0.f;
  if (tid < 200) {
    int kk = tid % 25, opp = tid / 25;
    v2f w; w.x = w_conv1[opp * 50 + kk]; w.y = w_conv1[opp * 50 + 25 + kk];
    wL[opp * 25 + kk] = w;
  }

  v2f sc1, sh1, sc2, sh2, sc3, sh3;
  {
    int c0 = 2 * op, c1 = 2 * op + 1;
    sc1.x = bn1[c0] * rsqrtf(bn1[48 + c0] + 1e-5f);
    sc1.y = bn1[c1] * rsqrtf(bn1[48 + c1] + 1e-5f);
    sh1.x = bn1[16 + c0] - bn1[32 + c0] * sc1.x;
    sh1.y = bn1[16 + c1] - bn1[32 + c1] * sc1.y;
    sc2.x = bn2[c0] * rsqrtf(bn2[48 + c0] + 1e-5f);
    sc2.y = bn2[c1] * rsqrtf(bn2[48 + c1] + 1e-5f);
    sh2.x = bn2[16 + c0] - bn2[32 + c0] * sc2.x;
    sh2.y = bn2[16 + c1] - bn2[32 + c1] * sc2.y;
  }
  v2f wd[3], we[3];
#pragma unroll
  for (int k = 0; k < 3; ++k) {
    wd[k].x = w_dw[6 * op + k];     wd[k].y = w_dw[6 * op + 3 + k];
    we[k].x = w_sdw[6 * op + k];    we[k].y = w_sdw[6 * op + 3 + k];
  }
  __syncthreads();

  float xw[48];
#pragma unroll
  for (int i = 0; i < 12; ++i) *(float4*)&xw[4 * i] = *(const float4*)&xs[T0 + 4 * i];
  v2f ce[20];
#pragma unroll
  for (int j = 0; j < 20; ++j) { ce[j].x = 0.f; ce[j].y = 0.f; }
#pragma unroll
  for (int k = 0; k < 25; ++k) {
    v2f wt = wL[op * 25 + k];
#pragma unroll
    for (int j = 0; j < 20; ++j) ce[j] += wt * xw[j + k + 2];
  }
  v2f zero; zero.x = 0.f; zero.y = 0.f;
#pragma unroll
  for (int j = 0; j < 20; ++j) {
    int t = T0 - 2 + j;
    v2f v = elu2(ce[j] * sc1 + sh1);
    ce[j] = ((unsigned)t < (unsigned)Tn) ? v : zero;
  }

  v2f d[18];
#pragma unroll
  for (int j = 0; j < 18; ++j) {
    int t = T0 - 1 + j;
    v2f a = ce[j] * wd[0] + ce[j + 1] * wd[1] + ce[j + 2] * wd[2];
    v2f v = elu2(a * sc2 + sh2);
    d[j] = ((unsigned)t < (unsigned)Tn) ? v : zero;
  }

#pragma unroll
  for (int r = 0; r < 8; ++r) {
    v2f s0 = d[2 * r] * we[0] + d[2 * r + 1] * we[1] + d[2 * r + 2] * we[2];
    v2f s1 = d[2 * r + 1] * we[0] + d[2 * r + 2] * we[1] + d[2 * r + 3] * we[2];
    float4 st; st.x = s0.x; st.y = s0.y; st.z = s1.x; st.w = s1.y;
    *(float4*)&s1p[op * 522 + T0 + 2 * r] = st;
  }

  const int oq = tid & 3, tgp = tid >> 2;
  v2f wA[16], wB[16];
#pragma unroll
  for (int q = 0; q < 16; ++q) {
    wA[q].x = w_spw[(4 * oq) * 16 + q];     wA[q].y = w_spw[(4 * oq + 1) * 16 + q];
    wB[q].x = w_spw[(4 * oq + 2) * 16 + q]; wB[q].y = w_spw[(4 * oq + 3) * 16 + q];
  }
  {
    int c0 = 4 * oq;
    sc3.x = bn3[c0] * rsqrtf(bn3[48 + c0] + 1e-5f);
    sc3.y = bn3[c0 + 1] * rsqrtf(bn3[48 + c0 + 1] + 1e-5f);
    sh3.x = bn3[16 + c0] - bn3[32 + c0] * sc3.x;
    sh3.y = bn3[16 + c0 + 1] - bn3[32 + c0 + 1] * sc3.y;
  }
  v2f sc3b, sh3b;
  {
    int c0 = 4 * oq + 2;
    sc3b.x = bn3[c0] * rsqrtf(bn3[48 + c0] + 1e-5f);
    sc3b.y = bn3[c0 + 1] * rsqrtf(bn3[48 + c0 + 1] + 1e-5f);
    sh3b.x = bn3[16 + c0] - bn3[32 + c0] * sc3b.x;
    sh3b.y = bn3[16 + c0 + 1] - bn3[32 + c0 + 1] * sc3b.y;
  }
  v2f tsA = zero, tsB = zero;
  __syncthreads();
#pragma unroll
  for (int tt = 0; tt < 8; ++tt) {
    int t = tgp + 64 * tt;
    if (tt < 7 || tgp < Tn - 448) {
      v2f aA = zero, aB = zero;
#pragma unroll
      for (int opr = 0; opr < 8; ++opr) {
        v2f inq = s1p[opr * 522 + t];
        aA += wA[2 * opr] * inq.x;  aA += wA[2 * opr + 1] * inq.y;
        aB += wB[2 * opr] * inq.x;  aB += wB[2 * opr + 1] * inq.y;
      }
      tsA += elu2(aA * sc3 + sh3);
      tsB += elu2(aB * sc3b + sh3b);
    }
  }
#pragma unroll
  for (int dd = 4; dd <= 32; dd <<= 1) {
    tsA.x += __shfl_xor(tsA.x, dd, 64); tsA.y += __shfl_xor(tsA.y, dd, 64);
    tsB.x += __shfl_xor(tsB.x, dd, 64); tsB.y += __shfl_xor(tsB.y, dd, 64);
  }
  if ((tid & 63) < 4) {
    float4 st; st.x = tsA.x; st.y = tsA.y; st.z = tsB.x; st.w = tsB.y;
    *(float4*)&red[(tid >> 6) * 16 + oq * 4] = st;
  }
  __syncthreads();
  if (tid < 16)
    feats[n * 16 + tid] =
        (red[tid] + red[16 + tid] + red[32 + tid] + red[48 + tid]) * (1.f / 500.f);
}

// ---------------------------------------------------------------------------
// GAT layer. Grid 256 = (b, i-half); block 512 = (head-half th) x 256.
// Row-parallel softmax: row ir owned by 8 contiguous lanes of one wave ->
// shfl-xor(width 8) reductions, wave-private al rows, NO barrier in head loop.
// Pitches: al/Mlg 66 (2-way conflicts = free), sS transposed [h][64].
template <int FIN, int LAYER>
__global__ __launch_bounds__(512) void gat_kernel(
    const float* __restrict__ Xa,
    const float* __restrict__ node_embed, const int* __restrict__ edges,
    const float* __restrict__ se_w1, const float* __restrict__ se_w2,
    const float* __restrict__ gsum_in,
    const float* __restrict__ W, const float* __restrict__ a_src,
    const float* __restrict__ a_dst, const float* __restrict__ bias,
    const float* __restrict__ bnp, const float* __restrict__ skip_w,
    float* __restrict__ out, float* __restrict__ gsum_out)
{
  constexpr int XLS = 0;                 // 8448 (ne aliased in [0,1024) pre-P4)
  constexpr int AL  = 8448;              // 2 x 32 x 66 = 4224
  constexpr int MLG = AL + 4224;         // 32 x 66 = 2112 (doubles as Ms counts)
  constexpr int XS  = MLG + 2112;        // 64*FIN
  constexpr int SS  = XS + 64 * FIN;     // 4 x 64
  constexpr int DS  = SS + 256;          // 32 x 4
  constexpr int CMB = DS + 128;          // 256 x 4
  constexpr int RS  = CMB + 1024;        // 32
  constexpr int SEA = RS + 32;           // 32
  constexpr int GT  = SEA + 32;          // 32
  constexpr int R8  = GT + 32;           // 8
  constexpr int TOT = R8 + 8;
  __shared__ float sm[TOT];

  const int b = blockIdx.x >> 1;
  const int i0 = (blockIdx.x & 1) * 32;
  const int tid = threadIdx.x;
  const int th = tid >> 8;               // head-half
  const int tl = tid & 255;

  // ---- P0: zero + loads ----
  if (tid < 32) sm[SEA + tid] = 0.f;
  if (LAYER == 2 && tid >= 32 && tid < 64)
    sm[GT + tid - 32] = gsum_in[tid - 32] * (1.f / 8192.f);
  for (int i = tid; i < 1024; i += 512) sm[XLS + i] = node_embed[i];
  for (int i = tid; i < 2112; i += 512) sm[MLG + i] = 0.f;
  for (int i = tid; i < 64 * FIN; i += 512) sm[XS + i] = Xa[b * 64 * FIN + i];
  int e0 = 0, e1 = 0;
  if (tid < 256) { e0 = edges[tid]; e1 = edges[256 + tid]; }
  __syncthreads();

  // ---- P1: A-half = relu(ne[i0+ir] . ne[j]); edge scatter; SE hidden ----
  for (int idx = tid; idx < 2048; idx += 512) {
    int ir = idx >> 6, j = idx & 63;
    const float* ni = sm + XLS + (i0 + ir) * 16;
    const float* nj = sm + XLS + j * 16;
    float a = 0.f;
#pragma unroll
    for (int f = 0; f < 16; ++f) a += ni[f] * nj[f];
    sm[AL + ir * 66 + j] = a > 0.f ? a : 0.f;
  }
  if (tid < 256 && e0 >= i0 && e0 < i0 + 32)
    atomicAdd(&sm[MLG + (e0 - i0) * 66 + e1], 1.f);
  if (LAYER == 2 && tid >= 256 && tid < 264) {
    float a = 0.f;
    for (int f = 0; f < 32; ++f) a += sm[GT + f] * se_w1[(tid - 256) * 32 + f];
    sm[R8 + tid - 256] = a > 0.f ? a : 0.f;
  }
  __syncthreads();

  // ---- P2: row sums of A; SE gate ----
  if (tid < 32) {
    float s = 0.f;
    for (int j = 0; j < 64; ++j) s += sm[AL + tid * 66 + j];
    sm[RS + tid] = s + 1e-6f;
  }
  if (LAYER == 2 && tid >= 256 && tid < 288) {
    float a = 0.f;
    for (int k = 0; k < 8; ++k) a += sm[R8 + k] * se_w2[(tid - 256) * 8 + k];
    sm[GT + tid - 256] = 1.f / (1.f + __expf(-a));
  }
  __syncthreads();

  // ---- P3: Mlg in place; gate Xs (layer 2) ----
  for (int idx = tid; idx < 2048; idx += 512) {
    int ir = idx >> 6, j = idx & 63;
    float dyn = (sm[AL + ir * 66 + j] / sm[RS + ir] > 0.1f) ? 1.f : 0.f;
    float M = (i0 + ir == j) ? 1.f : (sm[MLG + ir * 66 + j] + dyn);
    sm[MLG + ir * 66 + j] = (M > 0.f) ? __logf(M) : -INFINITY;
  }
  if (LAYER == 2) {
    for (int i = tid; i < 64 * FIN; i += 512) sm[XS + i] *= sm[GT + (i & 31)];
  }
  __syncthreads();

  // ---- P4: xl = X W (pitch 132), 16 rows/thread ----
  {
    const int fo = tid & 127, q4r = tid >> 7;
    float wcol[FIN];
#pragma unroll
    for (int q = 0; q < FIN; ++q) wcol[q] = W[q * 128 + fo];
    for (int nn = q4r; nn < 64; nn += 4) {
      float acc = 0.f;
#pragma unroll
      for (int q = 0; q < FIN; ++q) acc += sm[XS + nn * FIN + q] * wcol[q];
      sm[XLS + nn * 132 + fo] = acc;
    }
  }
  __syncthreads();

  // ---- P5: attention terms: s for all j, d for the i-half ----
  if (tid < 256) {
    const int nn = tid >> 2, h = tid & 3;
    float s = 0.f;
    for (int q = 0; q < 32; ++q)
      s += sm[XLS + nn * 132 + h * 32 + q] * a_src[h * 32 + q];
    sm[SS + h * 64 + nn] = s;
  } else if (tid < 384) {
    const int idx = tid - 256, ir = idx >> 2, h = idx & 3;
    float d = 0.f;
    for (int q = 0; q < 32; ++q)
      d += sm[XLS + (i0 + ir) * 132 + h * 32 + q] * a_dst[h * 32 + q];
    sm[DS + ir * 4 + h] = d;
  }
  __syncthreads();

  // ---- P6: head loop (2 heads per thread-half), barrier-free ----
  const int ir = tl >> 3;                // row 0..31
  const int q4 = tl & 7;                 // f-quad / j-chunk
  float* alw = sm + AL + th * 2112;
  float accT[4] = {0.f, 0.f, 0.f, 0.f};
#pragma unroll
  for (int hh = 0; hh < 2; ++hh) {
    const int h = hh * 2 + th;
    const float dterm = sm[DS + ir * 4 + h];
    float lg[8];
    float mx = -INFINITY;
#pragma unroll
    for (int k = 0; k < 8; ++k) {
      int j = q4 * 8 + k;
      float e = dterm + sm[SS + h * 64 + j];
      e = e >= 0.f ? e : 0.2f * e;
      float v = e + sm[MLG + ir * 66 + j];
      lg[k] = v;
      mx = fmaxf(mx, v);
    }
    mx = fmaxf(mx, __shfl_xor(mx, 1, 8));
    mx = fmaxf(mx, __shfl_xor(mx, 2, 8));
    mx = fmaxf(mx, __shfl_xor(mx, 4, 8));
    float sum = 0.f;
#pragma unroll
    for (int k = 0; k < 8; ++k) { lg[k] = __expf(lg[k] - mx); sum += lg[k]; }
    sum += __shfl_xor(sum, 1, 8);
    sum += __shfl_xor(sum, 2, 8);
    sum += __shfl_xor(sum, 4, 8);
    const float inv = 1.f / sum;
#pragma unroll
    for (int k = 0; k < 8; ++k) alw[ir * 66 + q4 * 8 + k] = lg[k];
    // readers are the same 8 lanes (lockstep wave) -> no barrier needed
    float a0 = 0.f, a1 = 0.f, a2 = 0.f, a3 = 0.f;
#pragma unroll 8
    for (int j = 0; j < 64; ++j) {
      float av = alw[ir * 66 + j];
      float4 xv = *(const float4*)&sm[XLS + j * 132 + h * 32 + q4 * 4];
      a0 += av * xv.x; a1 += av * xv.y; a2 += av * xv.z; a3 += av * xv.w;
    }
    accT[0] += a0 * inv; accT[1] += a1 * inv;
    accT[2] += a2 * inv; accT[3] += a3 * inv;
  }

  // ---- P7: combine thread-halves, epilogue on th==0 ----
  if (th == 1) *(float4*)&sm[CMB + tl * 4] = make_float4(accT[0], accT[1], accT[2], accT[3]);
  __syncthreads();
  if (th == 0) {
    const float4 other = *(const float4*)&sm[CMB + tl * 4];
    accT[0] += other.x; accT[1] += other.y; accT[2] += other.z; accT[3] += other.w;
    const int i = i0 + ir;
    float res[4];
#pragma unroll
    for (int r = 0; r < 4; ++r) {
      int f = q4 * 4 + r;
      float bsc = bnp[f] * rsqrtf(bnp[96 + f] + 1e-5f);
      float bsh = bnp[32 + f] - bnp[64 + f] * bsc;
      float v = accT[r] * 0.25f + bias[f];
      v = v * bsc + bsh;
      float skip;
      if (LAYER == 1) {
        skip = 0.f;
#pragma unroll
        for (int q = 0; q < 16; ++q) skip += sm[XS + i * 16 + q] * skip_w[f * 16 + q];
      } else {
        skip = sm[XS + i * 32 + f];
      }
      v += skip;
      v = 0.5f * v * (1.f + erff(v * 0.70710678118654752440f));
      res[r] = v;
      atomicAdd(&sm[SEA + f], v);
    }
    *(float4*)&out[(b * 64 + i) * 32 + q4 * 4] = make_float4(res[0], res[1], res[2], res[3]);
  }
  __syncthreads();
  if (tid < 32) atomicAdd(&gsum_out[tid], sm[SEA + tid]);
}

// ---------------------------------------------------------------------------
// SE2 gate (redundant per block) + pool over C + classifier.
__global__ __launch_bounds__(64) void out_kernel(
    const float* __restrict__ tmp2, const float* __restrict__ gsum2,
    const float* __restrict__ se_w1, const float* __restrict__ se_w2,
    const float* __restrict__ clf_w, const float* __restrict__ clf_b,
    float* __restrict__ outp)
{
  __shared__ float mean32[32], r8[8], gate[32], pl[32];
  const int b = blockIdx.x, tid = threadIdx.x;
  if (tid < 32) mean32[tid] = gsum2[tid] * (1.f / 8192.f);
  __syncthreads();
  if (tid < 8) {
    float a = 0.f;
    for (int f = 0; f < 32; ++f) a += mean32[f] * se_w1[tid * 32 + f];
    r8[tid] = a > 0.f ? a : 0.f;
  }
  __syncthreads();
  if (tid < 32) {
    float a = 0.f;
    for (int k = 0; k < 8; ++k) a += r8[k] * se_w2[tid * 8 + k];
    gate[tid] = 1.f / (1.f + __expf(-a));
  }
  __syncthreads();
  if (tid < 32) {
    float a = 0.f;
    for (int n = 0; n < 64; ++n) a += tmp2[(b * 64 + n) * 32 + tid];
    pl[tid] = a * (1.f / 64.f) * gate[tid];
  }
  __syncthreads();
  if (tid < 2) {
    float a = clf_b[tid];
    for (int f = 0; f < 32; ++f) a += pl[f] * clf_w[tid * 32 + f];
    outp[b * 2 + tid] = a;
  }
}

// ---------------------------------------------------------------------------
extern "C" void kernel_launch(void* const* d_in, const int* in_sizes, int n_in,
                              void* d_out, int out_size, void* d_ws, size_t ws_size,
                              hipStream_t stream)
{
  const float* x          = (const float*)d_in[0];
  const int*   edges      = (const int*)d_in[1];
  const float* conv1_w    = (const float*)d_in[2];
  const float* bn_c1      = (const float*)d_in[3];
  const float* dw_w       = (const float*)d_in[4];
  const float* bn_c2      = (const float*)d_in[5];
  const float* sdw_w      = (const float*)d_in[6];
  const float* spw_w      = (const float*)d_in[7];
  const float* bn_c3      = (const float*)d_in[8];
  const float* node_embed = (const float*)d_in[9];
  const float* gat1_w     = (const float*)d_in[10];
  const float* gat1_asrc  = (const float*)d_in[11];
  const float* gat1_adst  = (const float*)d_in[12];
  const float* gat1_bias  = (const float*)d_in[13];
  const float* bn_g1      = (const float*)d_in[14];
  const float* skip1_w    = (const float*)d_in[15];
  const float* se1_w1     = (const float*)d_in[16];
  const float* se1_w2     = (const float*)d_in[17];
  const float* gat2_w     = (const float*)d_in[18];
  const float* gat2_asrc  = (const float*)d_in[19];
  const float* gat2_adst  = (const float*)d_in[20];
  const float* gat2_bias  = (const float*)d_in[21];
  const float* bn_g2      = (const float*)d_in[22];
  const float* se2_w1     = (const float*)d_in[23];
  const float* se2_w2     = (const float*)d_in[24];
  const float* clf_w      = (const float*)d_in[25];
  const float* clf_b      = (const float*)d_in[26];

  float* ws    = (float*)d_ws;
  float* feats = ws;             // 131072 floats  [B*C, 16]
  float* tmp1  = ws + 131072;    // 262144         [B*C, 32]
  float* tmp2  = ws + 393216;    // 262144         [B*C, 32]
  float* gs    = ws + 655360;    // 64: gsum1[32] | gsum2[32]

  feat_kernel<<<Bn * Cn, 256, 0, stream>>>(x, conv1_w, bn_c1, dw_w, bn_c2,
                                           sdw_w, spw_w, bn_c3, feats, gs);
  gat_kernel<16, 1><<<Bn * 2, 512, 0, stream>>>(
      feats, node_embed, edges, nullptr, nullptr, nullptr,
      gat1_w, gat1_asrc, gat1_adst, gat1_bias, bn_g1, skip1_w, tmp1, gs);
  gat_kernel<32, 2><<<Bn * 2, 512, 0, stream>>>(
      tmp1, node_embed, edges, se1_w1, se1_w2, gs,
      gat2_w, gat2_asrc, gat2_adst, gat2_bias, bn_g2, nullptr, tmp2, gs + 32);
  out_kernel<<<Bn, 64, 0, stream>>>(tmp2, gs + 32, se2_w1, se2_w2, clf_w, clf_b,
                                    (float*)d_out);
}